// Round 2
// baseline (481.251 us; speedup 1.0000x reference)
//
#include <hip/hip_runtime.h>
#include <hip/hip_bf16.h>

// CrossBandWindowAttentionWav: B_=2048 windows, N=64 tok, C=384, 6 heads
// (qk head_dim=16, v head_dim=64), rel-pos bias table 225x6, mask (1024,64,64).
// Pipeline: prep(weights->bf16 NxK, bias table) -> GEMM q -> GEMM k|v (v stored
// transposed per window) -> fused window attention -> GEMM proj (fp32 out).

typedef __attribute__((ext_vector_type(8))) short short8;
typedef __attribute__((ext_vector_type(4))) float f32x4;

__device__ __forceinline__ f32x4 mfma_b16(short8 a, short8 b, f32x4 c) {
  return __builtin_amdgcn_mfma_f32_16x16x32_bf16(a, b, c, 0, 0, 0);
}

__device__ __forceinline__ unsigned short f2bf(float x) {
  unsigned u = __builtin_bit_cast(unsigned, x);
  u = (u + 0x7fffu + ((u >> 16) & 1u)) >> 16;  // RNE; inputs finite
  return (unsigned short)u;
}

// ---------------------------------------------------------------- prep ------
__global__ void prep_k(const float* __restrict__ Wq, const float* __restrict__ Wk,
                       const float* __restrict__ Wv, const float* __restrict__ Wp,
                       const float* __restrict__ rpb, const int* __restrict__ rpi,
                       const float* __restrict__ bk, const float* __restrict__ bv,
                       unsigned short* __restrict__ Wq_t, unsigned short* __restrict__ Wkv_t,
                       unsigned short* __restrict__ Wp_t, float* __restrict__ bias6,
                       float* __restrict__ bias_kv) {
  const int T0 = 96 * 384, T1 = 480 * 384, T2 = 384 * 384, T3 = 6 * 4096, T4 = 480;
  int total = T0 + T1 + T2 + T3 + T4;
  for (int i = blockIdx.x * blockDim.x + threadIdx.x; i < total;
       i += gridDim.x * blockDim.x) {
    int r = i;
    if (r < T0) {                       // Wq_t[n][k] = Wq[k][n]
      int n = r / 384, k = r % 384;
      Wq_t[r] = f2bf(Wq[k * 96 + n]);
    } else if ((r -= T0) < T1) {        // rows 0..95 = Wk^T, 96..479 = Wv^T
      int n = r / 384, k = r % 384;
      Wkv_t[r] = f2bf(n < 96 ? Wk[k * 96 + n] : Wv[k * 384 + (n - 96)]);
    } else if ((r -= T1) < T2) {
      int n = r / 384, k = r % 384;
      Wp_t[r] = f2bf(Wp[k * 384 + n]);
    } else if ((r -= T2) < T3) {        // bias6[h][i][j] = rpb[rpi[i][j]][h]
      int h = r >> 12, ij = r & 4095;
      bias6[r] = rpb[rpi[ij] * 6 + h];
    } else {
      r -= T3;
      bias_kv[r] = (r < 96) ? bk[r] : bv[r - 96];
    }
  }
}

// ---------------------------------------------------------------- GEMM ------
// C[M=131072, N] = A[M,384] @ Bt[N,384]^T + bias.  BM=128, BN=96, BK=64.
// grid = (N/96, M/128)  (n-tile fastest so A panels stay hot in L2).
// A_F32: A is fp32 (convert to bf16 during staging) else bf16.
// OUT_MODE 0: bf16 out ld=96 (q) | 1: fp32 out ld=384 (final) |
//          2: split: col<96 -> k_out[M,96]; col>=96 -> vt_out[(win,d,tok)] bf16.
template <int A_F32, int OUT_MODE>
__global__ __launch_bounds__(256) void gemm_k(
    const void* __restrict__ Av, const unsigned short* __restrict__ Bt,
    const float* __restrict__ bias, void* __restrict__ Outv,
    unsigned short* __restrict__ k_out, unsigned short* __restrict__ vt_out) {
  __shared__ unsigned short Asub[128 * 64];  // rows 128B, XOR-swizzled
  __shared__ unsigned short Bsub[96 * 64];
  const int tid = threadIdx.x;
  const int lane = tid & 63, wid = tid >> 6;
  const int m0 = blockIdx.y * 128;
  const int n0 = blockIdx.x * 96;
  const int wm = (wid >> 1) * 64, wn = (wid & 1) * 48;

  f32x4 acc[4][3];
#pragma unroll
  for (int i = 0; i < 4; ++i)
#pragma unroll
    for (int j = 0; j < 3; ++j) acc[i][j] = (f32x4){0.f, 0.f, 0.f, 0.f};

  for (int kt = 0; kt < 6; ++kt) {
    __syncthreads();
    if (A_F32) {
      const float* A = (const float*)Av;
#pragma unroll
      for (int p = 0; p < 8; ++p) {
        int e = (p * 256 + tid) * 4;
        int row = e >> 6, kc = e & 63;
        const float4 v = *reinterpret_cast<const float4*>(
            A + (size_t)(m0 + row) * 384 + kt * 64 + kc);
        uint2 pk;
        pk.x = (unsigned)f2bf(v.x) | ((unsigned)f2bf(v.y) << 16);
        pk.y = (unsigned)f2bf(v.z) | ((unsigned)f2bf(v.w) << 16);
        *reinterpret_cast<uint2*>((char*)Asub +
                                  ((row * 128 + kc * 2) ^ ((row & 7) << 4))) = pk;
      }
    } else {
      const unsigned short* A = (const unsigned short*)Av;
#pragma unroll
      for (int p = 0; p < 4; ++p) {
        int e = (p * 256 + tid) * 8;
        int row = e >> 6, kc = e & 63;
        const float4 v = *reinterpret_cast<const float4*>(
            A + (size_t)(m0 + row) * 384 + kt * 64 + kc);
        *reinterpret_cast<float4*>((char*)Asub +
                                   ((row * 128 + kc * 2) ^ ((row & 7) << 4))) = v;
      }
    }
#pragma unroll
    for (int p = 0; p < 3; ++p) {
      int e = (p * 256 + tid) * 8;
      int row = e >> 6, kc = e & 63;
      const float4 v = *reinterpret_cast<const float4*>(
          Bt + (size_t)(n0 + row) * 384 + kt * 64 + kc);
      *reinterpret_cast<float4*>((char*)Bsub +
                                 ((row * 128 + kc * 2) ^ ((row & 7) << 4))) = v;
    }
    __syncthreads();

    const int lr = lane & 15;
    const int lk16 = (lane >> 4) * 16;  // byte offset of this lane's 8 bf16
#pragma unroll
    for (int ks = 0; ks < 2; ++ks) {
      const int kb = ks * 64 + lk16;
      short8 a[4], b[3];
#pragma unroll
      for (int mf = 0; mf < 4; ++mf) {
        int row = wm + mf * 16 + lr;
        a[mf] = *reinterpret_cast<const short8*>(
            (char*)Asub + ((row * 128 + kb) ^ ((row & 7) << 4)));
      }
#pragma unroll
      for (int nf = 0; nf < 3; ++nf) {
        int row = wn + nf * 16 + lr;
        b[nf] = *reinterpret_cast<const short8*>(
            (char*)Bsub + ((row * 128 + kb) ^ ((row & 7) << 4)));
      }
#pragma unroll
      for (int mf = 0; mf < 4; ++mf)
#pragma unroll
        for (int nf = 0; nf < 3; ++nf)
          acc[mf][nf] = mfma_b16(a[mf], b[nf], acc[mf][nf]);
    }
  }

  const int lr = lane & 15, lg = lane >> 4;
#pragma unroll
  for (int mf = 0; mf < 4; ++mf) {
#pragma unroll
    for (int nf = 0; nf < 3; ++nf) {
      int col = n0 + wn + nf * 16 + lr;
      float bb = bias[col];
#pragma unroll
      for (int r = 0; r < 4; ++r) {
        int row = m0 + wm + mf * 16 + lg * 4 + r;
        float val = acc[mf][nf][r] + bb;
        if (OUT_MODE == 0) {
          ((unsigned short*)Outv)[(size_t)row * 96 + col] = f2bf(val);
        } else if (OUT_MODE == 1) {
          ((float*)Outv)[(size_t)row * 384 + col] = val;
        } else {
          if (col < 96)
            k_out[(size_t)row * 96 + col] = f2bf(val);
          else  // v transposed per window: (win, d, tok)
            vt_out[(size_t)(row >> 6) * 24576 + (size_t)(col - 96) * 64 + (row & 63)] =
                f2bf(val);
        }
      }
    }
  }
}

// ----------------------------------------------------------- attention ------
// 1 block = 1 window. 4 waves; wave = one 16-row query tile (ti=wid).
// All S/P rows are wave-private -> no barriers inside the head loop.
__global__ __launch_bounds__(256) void attn_k(
    const unsigned short* __restrict__ q_buf, const unsigned short* __restrict__ k_buf,
    const unsigned short* __restrict__ vt_buf, const float* __restrict__ bias6,
    const float* __restrict__ mask, unsigned short* __restrict__ att_out) {
  __shared__ unsigned short vt_lds[384 * 64];  // [d][tok], 128B rows, swizzled
  __shared__ float S[64 * 68];
  __shared__ unsigned short P[64 * 64];        // 128B rows, swizzled
  const int w = blockIdx.x;
  const int tid = threadIdx.x;
  const int lane = tid & 63, wid = tid >> 6;

  const unsigned short* vsrc = vt_buf + (size_t)w * 24576;
#pragma unroll
  for (int p = 0; p < 12; ++p) {
    int e = (p * 256 + tid) * 8;
    int d = e >> 6, j = e & 63;
    const float4 v = *reinterpret_cast<const float4*>(vsrc + e);
    *reinterpret_cast<float4*>((char*)vt_lds + ((d * 128 + j * 2) ^ ((d & 7) << 4))) = v;
  }
  __syncthreads();

  const float* maskw = mask + (size_t)(w & 1023) * 4096;
  const int ti = wid;
  const int lr = lane & 15, lg = lane >> 4;
  const int srow = tid >> 2, sq = tid & 3;  // softmax: 4 lanes per row

  for (int h = 0; h < 6; ++h) {
    // ---- S = 0.25 * q k^T + bias + mask  (K=16 zero-padded to 32)
    short8 afrag = {0, 0, 0, 0, 0, 0, 0, 0};
    if (lg < 2)
      afrag = *reinterpret_cast<const short8*>(
          q_buf + (size_t)(w * 64 + ti * 16 + lr) * 96 + h * 16 + lg * 8);
#pragma unroll
    for (int tj = 0; tj < 4; ++tj) {
      short8 bfrag = {0, 0, 0, 0, 0, 0, 0, 0};
      if (lg < 2)
        bfrag = *reinterpret_cast<const short8*>(
            k_buf + (size_t)(w * 64 + tj * 16 + lr) * 96 + h * 16 + lg * 8);
      f32x4 zero = {0.f, 0.f, 0.f, 0.f};
      f32x4 s = mfma_b16(afrag, bfrag, zero);
#pragma unroll
      for (int r = 0; r < 4; ++r) {
        int i = ti * 16 + lg * 4 + r;
        int j = tj * 16 + lr;
        S[i * 68 + j] = s[r] * 0.25f + bias6[h * 4096 + i * 64 + j] + maskw[i * 64 + j];
      }
    }
    // ---- softmax (rows are wave-local)
    float buf[16];
    float mx = -3.0e38f;
#pragma unroll
    for (int c = 0; c < 16; ++c) {
      buf[c] = S[srow * 68 + sq * 16 + c];
      mx = fmaxf(mx, buf[c]);
    }
    mx = fmaxf(mx, __shfl_xor(mx, 1));
    mx = fmaxf(mx, __shfl_xor(mx, 2));
    float sum = 0.f;
#pragma unroll
    for (int c = 0; c < 16; ++c) {
      buf[c] = __expf(buf[c] - mx);
      sum += buf[c];
    }
    sum += __shfl_xor(sum, 1);
    sum += __shfl_xor(sum, 2);
    float inv = 1.0f / sum;
#pragma unroll
    for (int c = 0; c < 16; c += 2) {
      unsigned pk = (unsigned)f2bf(buf[c] * inv) | ((unsigned)f2bf(buf[c + 1] * inv) << 16);
      *reinterpret_cast<unsigned*>(
          (char*)P + ((srow * 128 + (sq * 16 + c) * 2) ^ ((srow & 7) << 4))) = pk;
    }
    // ---- out_h = P @ v_h  (K=64 -> 2 MFMAs per tile)
    short8 pa[2];
#pragma unroll
    for (int ks = 0; ks < 2; ++ks) {
      int i = ti * 16 + lr;
      pa[ks] = *reinterpret_cast<const short8*>(
          (char*)P + ((i * 128 + ks * 64 + lg * 16) ^ ((i & 7) << 4)));
    }
#pragma unroll
    for (int td = 0; td < 4; ++td) {
      f32x4 o = {0.f, 0.f, 0.f, 0.f};
#pragma unroll
      for (int ks = 0; ks < 2; ++ks) {
        int dd = h * 64 + td * 16 + lr;
        short8 vb = *reinterpret_cast<const short8*>(
            (char*)vt_lds + ((dd * 128 + ks * 64 + lg * 16) ^ ((dd & 7) << 4)));
        o = mfma_b16(pa[ks], vb, o);
      }
#pragma unroll
      for (int r = 0; r < 4; ++r) {
        int token = w * 64 + ti * 16 + lg * 4 + r;
        int col = h * 64 + td * 16 + lr;
        att_out[(size_t)token * 384 + col] = f2bf(o[r]);
      }
    }
  }
}

// -------------------------------------------------------------- launch ------
extern "C" void kernel_launch(void* const* d_in, const int* in_sizes, int n_in,
                              void* d_out, int out_size, void* d_ws, size_t ws_size,
                              hipStream_t stream) {
  const float* x    = (const float*)d_in[0];
  const float* cx   = (const float*)d_in[1];
  const int*   rpi  = (const int*)d_in[2];
  const float* mask = (const float*)d_in[3];
  const float* Wq   = (const float*)d_in[4];
  const float* bq   = (const float*)d_in[5];
  const float* Wk   = (const float*)d_in[6];
  const float* bk   = (const float*)d_in[7];
  const float* Wv   = (const float*)d_in[8];
  const float* bv   = (const float*)d_in[9];
  const float* Wp   = (const float*)d_in[10];
  const float* bp   = (const float*)d_in[11];
  const float* rpb  = (const float*)d_in[12];

  char* ws = (char*)d_ws;
  unsigned short* Wq_t   = (unsigned short*)(ws + 0);        //  73,728 B
  unsigned short* Wkv_t  = (unsigned short*)(ws + 73728);    // 368,640 B
  unsigned short* Wp_t   = (unsigned short*)(ws + 442368);   // 294,912 B
  float*          bias6  = (float*)(ws + 737280);            //  98,304 B
  float*          biaskv = (float*)(ws + 835584);            //   1,920 B
  const size_t MB = 1u << 20;
  unsigned short* q_buf  = (unsigned short*)(ws + MB);                        // 25,165,824 B
  unsigned short* k_buf  = (unsigned short*)(ws + MB + 25165824u);            // 25,165,824 B
  unsigned short* vt_buf = (unsigned short*)(ws + MB + 50331648u);            // 100,663,296 B
  unsigned short* att    = (unsigned short*)(ws + MB + 150994944u);           // 100,663,296 B
  // total workspace use: 252,706,816 B

  prep_k<<<256, 256, 0, stream>>>(Wq, Wk, Wv, Wp, rpb, rpi, bk, bv,
                                  Wq_t, Wkv_t, Wp_t, bias6, biaskv);
  gemm_k<1, 0><<<dim3(1, 1024), 256, 0, stream>>>(x, Wq_t, bq, q_buf, nullptr, nullptr);
  gemm_k<1, 2><<<dim3(5, 1024), 256, 0, stream>>>(cx, Wkv_t, biaskv, nullptr, k_buf, vt_buf);
  attn_k<<<2048, 256, 0, stream>>>(q_buf, k_buf, vt_buf, bias6, mask, att);
  gemm_k<0, 1><<<dim3(4, 1024), 256, 0, stream>>>(att, Wp_t, bp, d_out, nullptr, nullptr);
}